// Round 4
// baseline (66.825 us; speedup 1.0000x reference)
//
#include <hip/hip_runtime.h>

// Mamba-2 SSD forward. B=2, L=4096, H=16, P=S=64, chunk=64, n=64 chunks.
// K1: per chunk: M = L∘(C·B^T) (bf16 ws, frag-ready), Cs = dfs∘C (bf16 ws),
//     h_final^T (bf16 ws), chunk decay. All ws tiles pre-swizzled.
// K2: in-place inter-chunk scan on h (bf16 storage, fp32 carry) — layout-transparent.
// K3: LDS-free, barrier-free: Y^T = X^T·M^T + h^T·Cs^T, float4 stores.

#define BSZ 2
#define LSEQ 4096
#define NH 16
#define NC 64
#define NCH (BSZ * NH * NC)      // 2048 chunk tasks
#define SCAN_G 8
#define CHW 4096                 // ushort elems per chunk ws tile
#define TILE_USHORTS ((size_t)NCH * CHW)

typedef float f32x4 __attribute__((ext_vector_type(4)));
typedef __bf16 bf16x8 __attribute__((ext_vector_type(8)));

union FragU { uint4 u; bf16x8 b; };

__device__ __forceinline__ unsigned short f2b(float x) {
    union { float f; unsigned u; } c; c.f = x;
    unsigned r = c.u + 0x7fffu + ((c.u >> 16) & 1u);   // RNE bf16
    return (unsigned short)(r >> 16);
}
__device__ __forceinline__ float b2f(unsigned short v) {
    union { unsigned u; float f; } c; c.u = ((unsigned)v) << 16;
    return c.f;
}

// element-index swizzles, 64 ushort per row; XOR on col bits 3..5 keeps 16B groups aligned
__device__ __forceinline__ int rm_e(int row, int k) { return row * 64 + (k ^ ((row & 7) << 3)); }
__device__ __forceinline__ int tr_e(int row, int k) { return row * 64 + (k ^ (((row >> 1) & 7) << 3)); }

// fragment readers (work on LDS or global ushort arrays)
__device__ __forceinline__ bf16x8 frag_rm(const unsigned short* buf, int tile, int kk, int l) {
    FragU f; f.u = *(const uint4*)&buf[rm_e(tile * 16 + (l & 15), kk * 32 + ((l >> 4) << 3))];
    return f.b;
}
__device__ __forceinline__ bf16x8 frag_tr(const unsigned short* buf, int tile, int kk, int l) {
    FragU f; f.u = *(const uint4*)&buf[tr_e(tile * 16 + (l & 15), kk * 32 + ((l >> 4) << 3))];
    return f.b;
}

// ---------------- K1 ----------------
__global__ __launch_bounds__(256) void ssd_k1(
    const float* __restrict__ Xg, const float* __restrict__ Ag,
    const float* __restrict__ Bg, const float* __restrict__ Cg,
    unsigned short* __restrict__ hws, unsigned short* __restrict__ Mws,
    unsigned short* __restrict__ Csws, float* __restrict__ dws)
{
    __shared__ __align__(16) unsigned short sBrm[64 * 64];  // B [j][s]
    __shared__ __align__(16) unsigned short sCrm[64 * 64];  // C [i][s]
    __shared__ __align__(16) unsigned short sBt[64 * 64];   // B^T [s][c]
    __shared__ __align__(16) unsigned short sXt[64 * 64];   // (dte∘X)^T [p][c]
    __shared__ float sE[64], sR[64], sDte[64];

    const int tid = threadIdx.x;
    const int l = tid & 63;
    const int w = tid >> 6;
    const int n = blockIdx.x & (NC - 1);
    const int h = (blockIdx.x >> 6) & (NH - 1);
    const int b = blockIdx.x >> 10;
    const int row0 = b * LSEQ + n * 64;
    const unsigned chb = (unsigned)blockIdx.x * CHW;

    // issue global loads early
    float4 xv[4], bv[4], cv[4];
    const int p0 = (tid & 15) * 4;
    #pragma unroll
    for (int it = 0; it < 4; ++it) {
        const int c = (tid >> 4) + it * 16;
        const unsigned g = ((unsigned)(row0 + c) * NH + h) * 64 + p0;
        xv[it] = *(const float4*)&Xg[g];
        bv[it] = *(const float4*)&Bg[g];
        cv[it] = *(const float4*)&Cg[g];
    }
    // wave0: inclusive cumsum of A, decay factors
    if (tid < 64) {
        float a = Ag[(unsigned)(row0 + tid) * NH + h];
        #pragma unroll
        for (int off = 1; off < 64; off <<= 1) {
            float v = __shfl_up(a, off, 64);
            if (tid >= off) a += v;
        }
        const float a63 = __shfl(a, 63, 64);
        sE[tid] = __expf(a);
        sR[tid] = __expf(-a);
        sDte[tid] = __expf(a63 - a);
        if (tid == 63) dws[blockIdx.x] = __expf(a63);
    }
    __syncthreads();

    // stage LDS tiles + write Cs (= E[i]∘C) straight to ws (pre-swizzled)
    #pragma unroll
    for (int it = 0; it < 4; ++it) {
        const int c = (tid >> 4) + it * 16;
        const float dte = sDte[c];
        const float Ec = sE[c];
        ushort4 bw; bw.x = f2b(bv[it].x); bw.y = f2b(bv[it].y); bw.z = f2b(bv[it].z); bw.w = f2b(bv[it].w);
        ushort4 cw; cw.x = f2b(cv[it].x); cw.y = f2b(cv[it].y); cw.z = f2b(cv[it].z); cw.w = f2b(cv[it].w);
        *(ushort4*)&sBrm[rm_e(c, p0)] = bw;
        *(ushort4*)&sCrm[rm_e(c, p0)] = cw;
        sBt[tr_e(p0 + 0, c)] = bw.x;
        sBt[tr_e(p0 + 1, c)] = bw.y;
        sBt[tr_e(p0 + 2, c)] = bw.z;
        sBt[tr_e(p0 + 3, c)] = bw.w;
        sXt[tr_e(p0 + 0, c)] = f2b(xv[it].x * dte);
        sXt[tr_e(p0 + 1, c)] = f2b(xv[it].y * dte);
        sXt[tr_e(p0 + 2, c)] = f2b(xv[it].z * dte);
        sXt[tr_e(p0 + 3, c)] = f2b(xv[it].w * dte);
        ushort4 sw; sw.x = f2b(cv[it].x * Ec); sw.y = f2b(cv[it].y * Ec);
        sw.z = f2b(cv[it].z * Ec); sw.w = f2b(cv[it].w * Ec);
        *(ushort4*)&Csws[chb + rm_e(c, p0)] = sw;
    }
    __syncthreads();

    const f32x4 zero = {0.f, 0.f, 0.f, 0.f};
    // mm1T: D[j][i] = sum_s B[j][s] C[i][s] = CB[i][j]; wave w owns j in [16w,16w+16)
    // mmH:  D[s][p] = sum_c B[c][s] (dte X)[c][p] = h[s][p]; wave w owns s-rows
    f32x4 accT[4] = {zero, zero, zero, zero};
    f32x4 accH[4] = {zero, zero, zero, zero};
    #pragma unroll
    for (int kk = 0; kk < 2; ++kk) {
        const bf16x8 aB = frag_rm(sBrm, w, kk, l);
        const bf16x8 aBt = frag_tr(sBt, w, kk, l);
        #pragma unroll
        for (int t = 0; t < 4; ++t) {
            accT[t] = __builtin_amdgcn_mfma_f32_16x16x32_bf16(aB, frag_rm(sCrm, t, kk, l), accT[t], 0, 0, 0);
            accH[t] = __builtin_amdgcn_mfma_f32_16x16x32_bf16(aBt, frag_tr(sXt, t, kk, l), accH[t], 0, 0, 0);
        }
    }

    const int il = (l >> 4) << 2;
    // M epilogue: lane holds D[j = w16+il+r][i = ti*16+(l&15)] -> M[i][j0..j0+3] ushort4
    const int j0 = w * 16 + il;
    float Rj[4];
    #pragma unroll
    for (int r = 0; r < 4; ++r) Rj[r] = sR[j0 + r];
    #pragma unroll
    for (int ti = 0; ti < 4; ++ti) {
        const int i = ti * 16 + (l & 15);
        const float Ei = sE[i];
        ushort4 m;
        m.x = (i >= j0 + 0) ? f2b(Ei * Rj[0] * accT[ti][0]) : (unsigned short)0;
        m.y = (i >= j0 + 1) ? f2b(Ei * Rj[1] * accT[ti][1]) : (unsigned short)0;
        m.z = (i >= j0 + 2) ? f2b(Ei * Rj[2] * accT[ti][2]) : (unsigned short)0;
        m.w = (i >= j0 + 3) ? f2b(Ei * Rj[3] * accT[ti][3]) : (unsigned short)0;
        *(ushort4*)&Mws[chb + rm_e(i, j0)] = m;
    }
    // h epilogue: lane holds D[s = w16+il+r][p = tp*16+(l&15)] -> h^T[p][s0..s0+3] ushort4
    const int s0 = w * 16 + il;
    #pragma unroll
    for (int tp = 0; tp < 4; ++tp) {
        const int p = tp * 16 + (l & 15);
        ushort4 o;
        o.x = f2b(accH[tp][0]); o.y = f2b(accH[tp][1]);
        o.z = f2b(accH[tp][2]); o.w = f2b(accH[tp][3]);
        *(ushort4*)&hws[chb + rm_e(p, s0)] = o;
    }
}

// ---------------- K2: scan (in-place, bf16 storage, fp32 carry) ----------------
__global__ __launch_bounds__(256) void ssd_scan(unsigned short* __restrict__ hws,
                                                const float* __restrict__ dws)
{
    __shared__ float sD[NC];
    const int tid = threadIdx.x;
    const int bh = blockIdx.x / SCAN_G;
    const int g = blockIdx.x % SCAN_G;
    if (tid < NC) sD[tid] = dws[bh * NC + tid];
    __syncthreads();

    unsigned* hw32 = (unsigned*)hws;
    const unsigned base = (unsigned)bh * NC * 2048u + g * 256u + tid;
    float cx = 0.f, cy = 0.f;
    unsigned cur = hw32[base];
    #pragma unroll 4
    for (int c = 0; c < NC; ++c) {
        unsigned nxt = 0;
        if (c < NC - 1) nxt = hw32[base + (c + 1) * 2048u];
        const float hx = b2f((unsigned short)(cur & 0xffffu));
        const float hy = b2f((unsigned short)(cur >> 16));
        hw32[base + c * 2048u] = (unsigned)f2b(cx) | ((unsigned)f2b(cy) << 16);
        const float d = sD[c];
        cx = d * cx + hx;
        cy = d * cy + hy;
        cur = nxt;
    }
}

// ---------------- K3: LDS-free, barrier-free ----------------
// Y[i][p] = sum_j M[i][j] X[j][p] + sum_s Cs[i][s] h_inter[s][p]
// computed output-transposed: D[row=p][col=i]; A-frags X^T, h^T; B-frags M, Cs (uint4 ws loads)
__global__ __launch_bounds__(256) void ssd_k3(
    const float* __restrict__ Xg, const unsigned short* __restrict__ Mws,
    const unsigned short* __restrict__ Csws, const unsigned short* __restrict__ hws,
    float* __restrict__ Yg)
{
    const int tid = threadIdx.x;
    const int l = tid & 63;
    const int w = tid >> 6;
    const int n = blockIdx.x & (NC - 1);
    const int h = (blockIdx.x >> 6) & (NH - 1);
    const int b = blockIdx.x >> 10;
    const int row0 = b * LSEQ + n * 64;
    const unsigned chb = (unsigned)blockIdx.x * CHW;

    // A-fragments: row p = w*16 + (l&15), k-contiguous 8
    const int p = w * 16 + (l & 15);
    bf16x8 aX[2], aH[2];
    #pragma unroll
    for (int kk = 0; kk < 2; ++kk) {
        const int c0 = kk * 32 + ((l >> 4) << 3);
        bf16x8 x;
        #pragma unroll
        for (int e = 0; e < 8; ++e)
            x[e] = (__bf16)Xg[((unsigned)(row0 + c0 + e) * NH + h) * 64 + p];
        aX[kk] = x;
        FragU f; f.u = *(const uint4*)&hws[chb + rm_e(p, c0)];
        aH[kk] = f.b;
    }

    const f32x4 zero = {0.f, 0.f, 0.f, 0.f};
    f32x4 accY[4] = {zero, zero, zero, zero};
    f32x4 accI[4] = {zero, zero, zero, zero};
    #pragma unroll
    for (int kk = 0; kk < 2; ++kk) {
        #pragma unroll
        for (int ti = 0; ti < 4; ++ti) {
            const int ke = kk * 32 + ((l >> 4) << 3);
            const int ic = ti * 16 + (l & 15);
            FragU mf; mf.u = *(const uint4*)&Mws[chb + rm_e(ic, ke)];
            FragU cf; cf.u = *(const uint4*)&Csws[chb + rm_e(ic, ke)];
            accY[ti] = __builtin_amdgcn_mfma_f32_16x16x32_bf16(aX[kk], mf.b, accY[ti], 0, 0, 0);
            accI[ti] = __builtin_amdgcn_mfma_f32_16x16x32_bf16(aH[kk], cf.b, accI[ti], 0, 0, 0);
        }
    }

    const int il = (l >> 4) << 2;
    const int pbase = w * 16 + il;
    #pragma unroll
    for (int ti = 0; ti < 4; ++ti) {
        const int i = ti * 16 + (l & 15);
        float4 o;
        o.x = accY[ti][0] + accI[ti][0];
        o.y = accY[ti][1] + accI[ti][1];
        o.z = accY[ti][2] + accI[ti][2];
        o.w = accY[ti][3] + accI[ti][3];
        *(float4*)&Yg[((unsigned)(row0 + i) * NH + h) * 64 + pbase] = o;
    }
}

extern "C" void kernel_launch(void* const* d_in, const int* in_sizes, int n_in,
                              void* d_out, int out_size, void* d_ws, size_t ws_size,
                              hipStream_t stream) {
    const float* X = (const float*)d_in[0];
    const float* A = (const float*)d_in[1];
    const float* Bm = (const float*)d_in[2];
    const float* Cm = (const float*)d_in[3];
    float* Y = (float*)d_out;
    unsigned short* hws = (unsigned short*)d_ws;        // 16.8 MB
    unsigned short* Mws = hws + TILE_USHORTS;           // 16.8 MB
    unsigned short* Csws = Mws + TILE_USHORTS;          // 16.8 MB
    float* dws = (float*)(Csws + TILE_USHORTS);         // 8 KB

    ssd_k1<<<NCH, 256, 0, stream>>>(X, A, Bm, Cm, hws, Mws, Csws, dws);
    ssd_scan<<<BSZ * NH * SCAN_G, 256, 0, stream>>>(hws, dws);
    ssd_k3<<<NCH, 256, 0, stream>>>(X, Mws, Csws, hws, Y);
}